// Round 6
// baseline (290.180 us; speedup 1.0000x reference)
//
#include <hip/hip_runtime.h>

typedef unsigned short ushort_t;
using bf16x8 = __attribute__((ext_vector_type(8))) short;
using f32x16 = __attribute__((ext_vector_type(16))) float;

#define KT 27
#define NV 65536

__device__ inline unsigned short f2bf(float f) {
  unsigned int u = __builtin_bit_cast(unsigned int, f);
  u += 0x7fffu + ((u >> 16) & 1u);
  return (unsigned short)(u >> 16);
}
__device__ inline float b2f(ushort_t u) {
  unsigned int x = ((unsigned int)u) << 16;
  return __builtin_bit_cast(float, x);
}

// merged prep: statsp zero (block 0), x fp32->bf16 (blocks 0..4095),
// W1,W2 [k][c][d] -> per-lane MFMA B frags (blocks 4096..5823)
// Wf[(k*8 + ks*2 + ct)*512 + l*8 + j] = bf16(W[k][ks*16 + (l>>5)*8 + j][ct*32 + (l&31)])
__global__ __launch_bounds__(256) void k_prep(const float* __restrict__ x,
                                              const float* __restrict__ W1,
                                              const float* __restrict__ W2,
                                              ushort_t* __restrict__ xb,
                                              ushort_t* __restrict__ Wf1,
                                              ushort_t* __restrict__ Wf2,
                                              float* __restrict__ statsp) {
  int b = blockIdx.x;
  int t = threadIdx.x;
  if (b == 0) statsp[t] = 0.f;
  if (b < 4096) {
    int i = b * 256 + t;  // float4 index
    float4 v = ((const float4*)x)[i];
    ushort4 o;
    o.x = f2bf(v.x); o.y = f2bf(v.y); o.z = f2bf(v.z); o.w = f2bf(v.w);
    ((ushort4*)xb)[i] = o;
  } else {
    int e = (b - 4096) * 256 + t;  // < 442368
    const float* W = W1; ushort_t* Wf = Wf1;
    if (e >= 221184) { e -= 221184; W = W2; Wf = Wf2; }
    int j = e & 7, l = (e >> 3) & 63, u = (e >> 9) & 7, k = e >> 12;
    int ks = u >> 1, ct = u & 1;
    int c = ks * 16 + (l >> 5) * 8 + j;
    int d = ct * 32 + (l & 31);
    Wf[e] = f2bf(W[(k << 12) + (c << 6) + d]);
  }
}

// Gather-GEMM conv, 32x32x16 MFMA, barrier-free K-loop + TAP-PARITY WAVE SPLIT.
// block = 256 thr = 4 waves over 64 voxels: wave w -> vox group g=w>>1 (32 vox),
// tap parity p=w&1 (even: k=0,2,..26 [14 taps]; odd: k=1,3,..25 [13 taps]).
// Partial accumulators combined through LDS at the end (one barrier).
// 1024 blocks = 4 blocks/CU = 16 waves/CU (2x R5's TLP).
// Wave-local LDS A tile (double-buffered, XOR-swizzled 16B chunks): no K-loop barriers.
// B frags register-direct from pre-swizzled Wf, half-tap reload pipeline (saves 32 VGPR).
// nbr read straight from global (8 lanes share one dword; L1-hot).
template<bool OBF16>
__global__ __launch_bounds__(256, 4) void k_conv(const ushort_t* __restrict__ src,  // [N][64] bf16
                                                 const int* __restrict__ nbr,       // [N][27]
                                                 const ushort_t* __restrict__ Wf,
                                                 void* __restrict__ houtv,          // [N][64]
                                                 float* __restrict__ gsum,
                                                 float* __restrict__ gsq) {
  __shared__ alignas(16) ushort_t As[4][2][2048];  // per-wave double-buffered 32x64 tile, 32 KB
  __shared__ float red[2][2][64];                  // stats partials per vox group, 1 KB

  const int t = threadIdx.x;
  const int lane = t & 63;
  const int w = t >> 6;
  const int g = w >> 1;            // vox subgroup
  const int p = w & 1;             // tap parity
  const int hh = lane >> 5;
  const int r31 = lane & 31;
  const int wbase = blockIdx.x * 64 + g * 32;
  const int nt = p ? 13 : 14;      // taps this wave owns: k = p + 2*i

  const int srow0 = lane >> 3;     // staging row (+8*i)
  const int sch = (lane & 7) * 8;  // channel offset (ushorts)
  const int s7l = lane & 7;

  f32x16 acc0 = {0,0,0,0,0,0,0,0,0,0,0,0,0,0,0,0};
  f32x16 acc1 = {0,0,0,0,0,0,0,0,0,0,0,0,0,0,0,0};

  uint4 rA[2][4];
  bf16x8 bB0[4], bB1[4];           // B half-fragments (ks 0,1) and (ks 2,3)

  auto ldA = [&](int i, uint4* r) {
    int k = p + 2 * i;
#pragma unroll
    for (int j = 0; j < 4; ++j) {
      int row = srow0 + j * 8;
      int idx = nbr[(wbase + row) * KT + k];
      uint4 v = {0u, 0u, 0u, 0u};
      if (idx >= 0) v = *(const uint4*)(src + idx * 64 + sch);
      r[j] = v;
    }
  };
  auto wrA = [&](int buf, const uint4* r) {
#pragma unroll
    for (int j = 0; j < 4; ++j) {
      int row = srow0 + j * 8;
      *(uint4*)(&As[w][buf][row * 64 + ((s7l ^ (row & 7)) * 8)]) = r[j];
    }
  };
  auto ldBh = [&](int i, int h, bf16x8* b) {
    const ushort_t* q = Wf + (p + 2 * i) * 4096 + h * 2048 + lane * 8;
#pragma unroll
    for (int u = 0; u < 4; ++u) b[u] = *(const bf16x8*)(q + u * 512);
  };
  auto computeh = [&](int buf, int h, const bf16x8* b) {
    const ushort_t* ar = &As[w][buf][r31 * 64];
    const int s7 = r31 & 7;
#pragma unroll
    for (int k2 = 0; k2 < 2; ++k2) {
      int ks = h * 2 + k2;
      bf16x8 af = *(const bf16x8*)(ar + (((ks * 2 + hh) ^ s7) * 8));
      acc0 = __builtin_amdgcn_mfma_f32_32x32x16_bf16(af, b[k2 * 2 + 0], acc0, 0, 0, 0);
      acc1 = __builtin_amdgcn_mfma_f32_32x32x16_bf16(af, b[k2 * 2 + 1], acc1, 0, 0, 0);
    }
  };

  // prologue
  ldA(0, rA[0]);
  ldA(1, rA[1]);
  ldBh(0, 0, bB0);
  ldBh(0, 1, bB1);
  wrA(0, rA[0]);

  // invariant at iter i: As[i&1] = tap i, rA[(i+1)&1] = tap i+1, bB* = B(tap i)
  for (int i = 0; i < nt; ++i) {
    const int cur = i & 1, nxt = cur ^ 1;
    const int i2 = (i + 2 < nt) ? i + 2 : nt - 1;
    const int i1 = (i + 1 < nt) ? i + 1 : nt - 1;
    ldA(i2, rA[cur]);
    wrA(nxt, rA[nxt]);
    computeh(cur, 0, bB0);       // uses bB0(tap i), then reload
    ldBh(i1, 0, bB0);
    computeh(cur, 1, bB1);
    ldBh(i1, 1, bB1);
  }

  // combine partials: odd waves write acc into their (now dead) own As region
  if (p) {
    float* myc = (float*)&As[w][0][0];   // 2048 floats, swizzled conflict-free
#pragma unroll
    for (int r = 0; r < 16; ++r) {
      myc[lane * 32 + ((r + lane) & 31)] = acc0[r];
      myc[lane * 32 + ((r + 16 + lane) & 31)] = acc1[r];
    }
  }
  __syncthreads();

  if (!p) {
    const float* pc = (const float*)&As[w + 1][0][0];
#pragma unroll
    for (int r = 0; r < 16; ++r) {
      acc0[r] += pc[lane * 32 + ((r + lane) & 31)];
      acc1[r] += pc[lane * 32 + ((r + 16 + lane) & 31)];
    }
    // epilogue: store h + per-channel stat partials
    // C/D (32x32): col = lane&31, row = (reg&3) + 8*(reg>>2) + 4*(lane>>5)
    const int orow0 = wbase + (hh << 2);
    float s0 = 0.f, q0 = 0.f, s1 = 0.f, q1 = 0.f;
#pragma unroll
    for (int reg = 0; reg < 16; ++reg) {
      int row = orow0 + (reg & 3) + 8 * (reg >> 2);
      float v0 = acc0[reg], v1 = acc1[reg];
      if (OBF16) {
        ushort_t* ho = (ushort_t*)houtv;
        ho[row * 64 + r31] = f2bf(v0);
        ho[row * 64 + 32 + r31] = f2bf(v1);
      } else {
        float* ho = (float*)houtv;
        ho[row * 64 + r31] = v0;
        ho[row * 64 + 32 + r31] = v1;
      }
      s0 += v0; q0 += v0 * v0;
      s1 += v1; q1 += v1 * v1;
    }
    s0 += __shfl_xor(s0, 32, 64); q0 += __shfl_xor(q0, 32, 64);
    s1 += __shfl_xor(s1, 32, 64); q1 += __shfl_xor(q1, 32, 64);
    if (hh == 0) {
      red[0][g][r31] = s0; red[0][g][32 + r31] = s1;
      red[1][g][r31] = q0; red[1][g][32 + r31] = q1;
    }
  }
  __syncthreads();
  if (t < 128) {
    int which = t >> 6, c = t & 63;
    float v = red[which][0][c] + red[which][1][c];
    atomicAdd((which ? gsq : gsum) + c, v);
  }
}

// BN1 (inline params from raw stats) + ReLU on bf16 h1, writes bf16 for conv2's gather
__global__ __launch_bounds__(256) void k_bn_relu(const ushort_t* __restrict__ h,
                                                 const float* __restrict__ gsum,
                                                 const float* __restrict__ gsq,
                                                 const float* __restrict__ gamma,
                                                 const float* __restrict__ beta,
                                                 ushort_t* __restrict__ ob) {
  __shared__ float sc[64], sh[64];
  int t = threadIdx.x;
  if (t < 64) {
    float mean = gsum[t] * (1.f / NV);
    float var = gsq[t] * (1.f / NV) - mean * mean;
    float rs = rsqrtf(var + 1e-5f);
    float s = gamma[t] * rs;
    sc[t] = s;
    sh[t] = beta[t] - mean * s;
  }
  __syncthreads();
  int i = blockIdx.x * 256 + t;    // uint4 index = 8 bf16
  int c0 = (i & 7) * 8;
  uint4 v = ((const uint4*)h)[i];
  const ushort_t* pu = (const ushort_t*)&v;
  uint4 o;
  ushort_t* po = (ushort_t*)&o;
#pragma unroll
  for (int n = 0; n < 8; ++n)
    po[n] = f2bf(fmaxf(0.f, b2f(pu[n]) * sc[c0 + n] + sh[c0 + n]));
  ((uint4*)ob)[i] = o;
}

// BN2 (inline params) + residual + ReLU, fp32 out
__global__ __launch_bounds__(256) void k_final(const float* __restrict__ h,
                                               const float* __restrict__ x,
                                               const float* __restrict__ gsum,
                                               const float* __restrict__ gsq,
                                               const float* __restrict__ gamma,
                                               const float* __restrict__ beta,
                                               float* __restrict__ out) {
  __shared__ float sc[64], sh[64];
  int t = threadIdx.x;
  if (t < 64) {
    float mean = gsum[t] * (1.f / NV);
    float var = gsq[t] * (1.f / NV) - mean * mean;
    float rs = rsqrtf(var + 1e-5f);
    float s = gamma[t] * rs;
    sc[t] = s;
    sh[t] = beta[t] - mean * s;
  }
  __syncthreads();
  int i = blockIdx.x * 256 + t;
  int c0 = (i << 2) & 63;
  float4 v = ((const float4*)h)[i];
  float4 xv = ((const float4*)x)[i];
  float4 o;
  o.x = fmaxf(0.f, v.x * sc[c0]     + sh[c0]     + xv.x);
  o.y = fmaxf(0.f, v.y * sc[c0 + 1] + sh[c0 + 1] + xv.y);
  o.z = fmaxf(0.f, v.z * sc[c0 + 2] + sh[c0 + 2] + xv.z);
  o.w = fmaxf(0.f, v.w * sc[c0 + 3] + sh[c0 + 3] + xv.w);
  ((float4*)out)[i] = o;
}

extern "C" void kernel_launch(void* const* d_in, const int* in_sizes, int n_in,
                              void* d_out, int out_size, void* d_ws, size_t ws_size,
                              hipStream_t stream) {
  const float* x   = (const float*)d_in[0];
  const int*   nbr = (const int*)d_in[1];
  const float* W1  = (const float*)d_in[2];
  const float* g1  = (const float*)d_in[3];
  const float* b1  = (const float*)d_in[4];
  const float* W2  = (const float*)d_in[5];
  const float* g2  = (const float*)d_in[6];
  const float* b2  = (const float*)d_in[7];
  float* out = (float*)d_out;
  char* ws = (char*)d_ws;

  // workspace layout (bytes, 256-aligned), total ~42.8 MB
  ushort_t* xb     = (ushort_t*)(ws);               // 8,388,608
  ushort_t* h1pre  = (ushort_t*)(ws + 8388608);     // 8,388,608 (bf16, pre-BN)
  ushort_t* h1post = (ushort_t*)(ws + 16777216);    // 8,388,608 (bf16, post-BN+ReLU)
  ushort_t* Wf1    = (ushort_t*)(ws + 25165824);    // 442,368
  ushort_t* Wf2    = (ushort_t*)(ws + 25608192);    // 442,368
  float*    h2raw  = (float*)(ws + 26050560);       // 16,777,216
  float*    statsp = (float*)(ws + 42827776);       // 256 floats
  float *gsum1 = statsp, *gsq1 = statsp + 64, *gsum2 = statsp + 128, *gsq2 = statsp + 192;

  k_prep<<<5824, 256, 0, stream>>>(x, W1, W2, xb, Wf1, Wf2, statsp);

  k_conv<true><<<1024, 256, 0, stream>>>(xb, nbr, Wf1, (void*)h1pre, gsum1, gsq1);
  k_bn_relu<<<2048, 256, 0, stream>>>(h1pre, gsum1, gsq1, g1, b1, h1post);
  k_conv<false><<<1024, 256, 0, stream>>>(h1post, nbr, Wf2, (void*)h2raw, gsum2, gsq2);

  k_final<<<4096, 256, 0, stream>>>(h2raw, x, gsum2, gsq2, g2, b2, out);
}

// Round 7
// 236.204 us; speedup vs baseline: 1.2285x; 1.2285x over previous
//
#include <hip/hip_runtime.h>

typedef unsigned short ushort_t;
using bf16x8 = __attribute__((ext_vector_type(8))) short;
using f32x16 = __attribute__((ext_vector_type(16))) float;

#define KT 27
#define NV 65536

__device__ inline unsigned short f2bf(float f) {
  unsigned int u = __builtin_bit_cast(unsigned int, f);
  u += 0x7fffu + ((u >> 16) & 1u);
  return (unsigned short)(u >> 16);
}
__device__ inline float b2f(ushort_t u) {
  unsigned int x = ((unsigned int)u) << 16;
  return __builtin_bit_cast(float, x);
}

// merged prep: statsp zero (block 0), x fp32->bf16 (blocks 0..4095),
// W1,W2 [k][c][d] -> per-lane MFMA B frags (blocks 4096..5823)
// Wf[(k*8 + ks*2 + ct)*512 + l*8 + j] = bf16(W[k][ks*16 + (l>>5)*8 + j][ct*32 + (l&31)])
__global__ __launch_bounds__(256) void k_prep(const float* __restrict__ x,
                                              const float* __restrict__ W1,
                                              const float* __restrict__ W2,
                                              ushort_t* __restrict__ xb,
                                              ushort_t* __restrict__ Wf1,
                                              ushort_t* __restrict__ Wf2,
                                              float* __restrict__ statsp) {
  int b = blockIdx.x;
  int t = threadIdx.x;
  if (b == 0) statsp[t] = 0.f;
  if (b < 4096) {
    int i = b * 256 + t;  // float4 index
    float4 v = ((const float4*)x)[i];
    ushort4 o;
    o.x = f2bf(v.x); o.y = f2bf(v.y); o.z = f2bf(v.z); o.w = f2bf(v.w);
    ((ushort4*)xb)[i] = o;
  } else {
    int e = (b - 4096) * 256 + t;  // < 442368
    const float* W = W1; ushort_t* Wf = Wf1;
    if (e >= 221184) { e -= 221184; W = W2; Wf = Wf2; }
    int j = e & 7, l = (e >> 3) & 63, u = (e >> 9) & 7, k = e >> 12;
    int ks = u >> 1, ct = u & 1;
    int c = ks * 16 + (l >> 5) * 8 + j;
    int d = ct * 32 + (l & 31);
    Wf[e] = f2bf(W[(k << 12) + (c << 6) + d]);
  }
}

// Gather-GEMM conv, 32x32x16 MFMA, barrier-free K-loop + tap-parity wave split.
// block = 256 thr = 4 waves over 64 voxels: wave w -> vox group g=w>>1 (32 vox),
// tap parity p=w&1 (even: taps 0,2,..,26 [14]; odd: 1,3,..,25 [13]).
// __launch_bounds__(256,3): 170-VGPR cap -> 12 waves/CU co-resident, NO spill
// (R6's (256,4)=128 cap spilled: WRITE_SIZE 252 MB. Register budget ~145 here.)
// Depth-3 A register pipeline (2-iteration gather slack), half-reload B pipeline,
// A-frag ds_reads hoisted before next tap's ds_writes. Loop fully unrolled (13
// literal iters, slot indices compile-time); even waves run tap 26 as a tail.
// Partial accumulators combined through LDS once at the end.
template<bool OBF16>
__global__ __launch_bounds__(256, 3) void k_conv(const ushort_t* __restrict__ src,  // [N][64] bf16
                                                 const int* __restrict__ nbr,       // [N][27]
                                                 const ushort_t* __restrict__ Wf,
                                                 void* __restrict__ houtv,          // [N][64]
                                                 float* __restrict__ gsum,
                                                 float* __restrict__ gsq) {
  __shared__ alignas(16) ushort_t As[4][2][2048];  // per-wave double-buffered 32x64 tile, 32 KB
  __shared__ float red[2][2][64];                  // stats partials per vox group, 1 KB

  const int t = threadIdx.x;
  const int lane = t & 63;
  const int w = t >> 6;
  const int g = w >> 1;            // vox subgroup
  const int p = w & 1;             // tap parity
  const int hh = lane >> 5;
  const int r31 = lane & 31;
  const int wbase = blockIdx.x * 64 + g * 32;
  const int ilast = 13 - p;        // last valid i (tap = p + 2*i)

  const int srow0 = lane >> 3;     // staging row (+8*j)
  const int sch = (lane & 7) * 8;  // channel offset (ushorts)
  const int s7l = lane & 7;

  f32x16 acc0 = {0,0,0,0,0,0,0,0,0,0,0,0,0,0,0,0};
  f32x16 acc1 = {0,0,0,0,0,0,0,0,0,0,0,0,0,0,0,0};

  uint4 rA[3][4];                  // depth-3 A pipeline (tap t lives in slot t%3... i-indexed)
  bf16x8 bB0[4], bB1[4];           // B half-fragments (ks 0,1) and (ks 2,3)

  auto ldA = [&](int i, uint4* r) {
    int k = p + 2 * i;
#pragma unroll
    for (int j = 0; j < 4; ++j) {
      int row = srow0 + j * 8;
      int idx = nbr[(wbase + row) * KT + k];
      uint4 v = {0u, 0u, 0u, 0u};
      if (idx >= 0) v = *(const uint4*)(src + idx * 64 + sch);
      r[j] = v;
    }
  };
  auto wrA = [&](int buf, const uint4* r) {
#pragma unroll
    for (int j = 0; j < 4; ++j) {
      int row = srow0 + j * 8;
      *(uint4*)(&As[w][buf][row * 64 + ((s7l ^ (row & 7)) * 8)]) = r[j];
    }
  };
  auto ldBh = [&](int i, int h, bf16x8* b) {
    const ushort_t* q = Wf + (p + 2 * i) * 4096 + h * 2048 + lane * 8;
#pragma unroll
    for (int u = 0; u < 4; ++u) b[u] = *(const bf16x8*)(q + u * 512);
  };

  // prologue: taps i=0,1,2 -> slots 0,1,2; stage i=0 to buf0; B(i=0)
  ldA(0, rA[0]);
  ldA(1, rA[1]);
  ldA(2, rA[2]);
  ldBh(0, 0, bB0);
  ldBh(0, 1, bB1);
  wrA(0, rA[0]);

  const int s7 = r31 & 7;
  // invariant at iter i: buf(i&1)=tap i staged; slots (i+1)%3,(i+2)%3 hold taps i+1,i+2
#pragma unroll
  for (int i = 0; i < 13; ++i) {
    const int cur = i & 1, nxt = cur ^ 1;
    int iA = i + 3; if (iA > ilast) iA = ilast;   // clamped prefetch targets
    int iB = i + 1; if (iB > ilast) iB = ilast;
    // hoisted A-frag reads for tap i (before next tap's ds_writes)
    bf16x8 af[4];
    const ushort_t* ar = &As[w][cur][r31 * 64];
#pragma unroll
    for (int ks = 0; ks < 4; ++ks)
      af[ks] = *(const bf16x8*)(ar + (((ks * 2 + hh) ^ s7) * 8));
    wrA(nxt, rA[(i + 1) % 3]);     // tap i+1 -> LDS (loaded 2 iters ago)
    ldA(iA, rA[i % 3]);            // refill freed slot with tap i+3
    acc0 = __builtin_amdgcn_mfma_f32_32x32x16_bf16(af[0], bB0[0], acc0, 0, 0, 0);
    acc1 = __builtin_amdgcn_mfma_f32_32x32x16_bf16(af[0], bB0[1], acc1, 0, 0, 0);
    acc0 = __builtin_amdgcn_mfma_f32_32x32x16_bf16(af[1], bB0[2], acc0, 0, 0, 0);
    acc1 = __builtin_amdgcn_mfma_f32_32x32x16_bf16(af[1], bB0[3], acc1, 0, 0, 0);
    ldBh(iB, 0, bB0);              // reload first half for tap i+1
    acc0 = __builtin_amdgcn_mfma_f32_32x32x16_bf16(af[2], bB1[0], acc0, 0, 0, 0);
    acc1 = __builtin_amdgcn_mfma_f32_32x32x16_bf16(af[2], bB1[1], acc1, 0, 0, 0);
    acc0 = __builtin_amdgcn_mfma_f32_32x32x16_bf16(af[3], bB1[2], acc0, 0, 0, 0);
    acc1 = __builtin_amdgcn_mfma_f32_32x32x16_bf16(af[3], bB1[3], acc1, 0, 0, 0);
    ldBh(iB, 1, bB1);              // reload second half for tap i+1
  }
  // tail: even waves compute tap 26 (i=13), already staged to buf1 by iter 12's wrA,
  // bB holds i=13 via iter 12's clamped reloads.
  if (p == 0) {
    bf16x8 af[4];
    const ushort_t* ar = &As[w][1][r31 * 64];
#pragma unroll
    for (int ks = 0; ks < 4; ++ks)
      af[ks] = *(const bf16x8*)(ar + (((ks * 2 + hh) ^ s7) * 8));
    acc0 = __builtin_amdgcn_mfma_f32_32x32x16_bf16(af[0], bB0[0], acc0, 0, 0, 0);
    acc1 = __builtin_amdgcn_mfma_f32_32x32x16_bf16(af[0], bB0[1], acc1, 0, 0, 0);
    acc0 = __builtin_amdgcn_mfma_f32_32x32x16_bf16(af[1], bB0[2], acc0, 0, 0, 0);
    acc1 = __builtin_amdgcn_mfma_f32_32x32x16_bf16(af[1], bB0[3], acc1, 0, 0, 0);
    acc0 = __builtin_amdgcn_mfma_f32_32x32x16_bf16(af[2], bB1[0], acc0, 0, 0, 0);
    acc1 = __builtin_amdgcn_mfma_f32_32x32x16_bf16(af[2], bB1[1], acc1, 0, 0, 0);
    acc0 = __builtin_amdgcn_mfma_f32_32x32x16_bf16(af[3], bB1[2], acc0, 0, 0, 0);
    acc1 = __builtin_amdgcn_mfma_f32_32x32x16_bf16(af[3], bB1[3], acc1, 0, 0, 0);
  }

  // combine partials: odd waves write acc into their (now dead) own As region
  // (+lane rotation -> 2-way bank alias max, free)
  if (p) {
    float* myc = (float*)&As[w][0][0];   // 2048 floats
#pragma unroll
    for (int r = 0; r < 16; ++r) {
      myc[lane * 32 + ((r + lane) & 31)] = acc0[r];
      myc[lane * 32 + ((r + 16 + lane) & 31)] = acc1[r];
    }
  }
  __syncthreads();

  if (!p) {
    const float* pc = (const float*)&As[w + 1][0][0];
#pragma unroll
    for (int r = 0; r < 16; ++r) {
      acc0[r] += pc[lane * 32 + ((r + lane) & 31)];
      acc1[r] += pc[lane * 32 + ((r + 16 + lane) & 31)];
    }
    // epilogue: store h + per-channel stat partials
    // C/D (32x32): col = lane&31, row = (reg&3) + 8*(reg>>2) + 4*(lane>>5)
    const int orow0 = wbase + (hh << 2);
    float s0 = 0.f, q0 = 0.f, s1 = 0.f, q1 = 0.f;
#pragma unroll
    for (int reg = 0; reg < 16; ++reg) {
      int row = orow0 + (reg & 3) + 8 * (reg >> 2);
      float v0 = acc0[reg], v1 = acc1[reg];
      if (OBF16) {
        ushort_t* ho = (ushort_t*)houtv;
        ho[row * 64 + r31] = f2bf(v0);
        ho[row * 64 + 32 + r31] = f2bf(v1);
      } else {
        float* ho = (float*)houtv;
        ho[row * 64 + r31] = v0;
        ho[row * 64 + 32 + r31] = v1;
      }
      s0 += v0; q0 += v0 * v0;
      s1 += v1; q1 += v1 * v1;
    }
    s0 += __shfl_xor(s0, 32, 64); q0 += __shfl_xor(q0, 32, 64);
    s1 += __shfl_xor(s1, 32, 64); q1 += __shfl_xor(q1, 32, 64);
    if (hh == 0) {
      red[0][g][r31] = s0; red[0][g][32 + r31] = s1;
      red[1][g][r31] = q0; red[1][g][32 + r31] = q1;
    }
  }
  __syncthreads();
  if (t < 128) {
    int which = t >> 6, c = t & 63;
    float v = red[which][0][c] + red[which][1][c];
    atomicAdd((which ? gsq : gsum) + c, v);
  }
}

// BN1 (inline params from raw stats) + ReLU on bf16 h1, writes bf16 for conv2's gather
__global__ __launch_bounds__(256) void k_bn_relu(const ushort_t* __restrict__ h,
                                                 const float* __restrict__ gsum,
                                                 const float* __restrict__ gsq,
                                                 const float* __restrict__ gamma,
                                                 const float* __restrict__ beta,
                                                 ushort_t* __restrict__ ob) {
  __shared__ float sc[64], sh[64];
  int t = threadIdx.x;
  if (t < 64) {
    float mean = gsum[t] * (1.f / NV);
    float var = gsq[t] * (1.f / NV) - mean * mean;
    float rs = rsqrtf(var + 1e-5f);
    float s = gamma[t] * rs;
    sc[t] = s;
    sh[t] = beta[t] - mean * s;
  }
  __syncthreads();
  int i = blockIdx.x * 256 + t;    // uint4 index = 8 bf16
  int c0 = (i & 7) * 8;
  uint4 v = ((const uint4*)h)[i];
  const ushort_t* pu = (const ushort_t*)&v;
  uint4 o;
  ushort_t* po = (ushort_t*)&o;
#pragma unroll
  for (int n = 0; n < 8; ++n)
    po[n] = f2bf(fmaxf(0.f, b2f(pu[n]) * sc[c0 + n] + sh[c0 + n]));
  ((uint4*)ob)[i] = o;
}

// BN2 (inline params) + residual + ReLU, fp32 out
__global__ __launch_bounds__(256) void k_final(const float* __restrict__ h,
                                               const float* __restrict__ x,
                                               const float* __restrict__ gsum,
                                               const float* __restrict__ gsq,
                                               const float* __restrict__ gamma,
                                               const float* __restrict__ beta,
                                               float* __restrict__ out) {
  __shared__ float sc[64], sh[64];
  int t = threadIdx.x;
  if (t < 64) {
    float mean = gsum[t] * (1.f / NV);
    float var = gsq[t] * (1.f / NV) - mean * mean;
    float rs = rsqrtf(var + 1e-5f);
    float s = gamma[t] * rs;
    sc[t] = s;
    sh[t] = beta[t] - mean * s;
  }
  __syncthreads();
  int i = blockIdx.x * 256 + t;
  int c0 = (i << 2) & 63;
  float4 v = ((const float4*)h)[i];
  float4 xv = ((const float4*)x)[i];
  float4 o;
  o.x = fmaxf(0.f, v.x * sc[c0]     + sh[c0]     + xv.x);
  o.y = fmaxf(0.f, v.y * sc[c0 + 1] + sh[c0 + 1] + xv.y);
  o.z = fmaxf(0.f, v.z * sc[c0 + 2] + sh[c0 + 2] + xv.z);
  o.w = fmaxf(0.f, v.w * sc[c0 + 3] + sh[c0 + 3] + xv.w);
  ((float4*)out)[i] = o;
}

extern "C" void kernel_launch(void* const* d_in, const int* in_sizes, int n_in,
                              void* d_out, int out_size, void* d_ws, size_t ws_size,
                              hipStream_t stream) {
  const float* x   = (const float*)d_in[0];
  const int*   nbr = (const int*)d_in[1];
  const float* W1  = (const float*)d_in[2];
  const float* g1  = (const float*)d_in[3];
  const float* b1  = (const float*)d_in[4];
  const float* W2  = (const float*)d_in[5];
  const float* g2  = (const float*)d_in[6];
  const float* b2  = (const float*)d_in[7];
  float* out = (float*)d_out;
  char* ws = (char*)d_ws;

  // workspace layout (bytes, 256-aligned), total ~42.8 MB
  ushort_t* xb     = (ushort_t*)(ws);               // 8,388,608
  ushort_t* h1pre  = (ushort_t*)(ws + 8388608);     // 8,388,608 (bf16, pre-BN)
  ushort_t* h1post = (ushort_t*)(ws + 16777216);    // 8,388,608 (bf16, post-BN+ReLU)
  ushort_t* Wf1    = (ushort_t*)(ws + 25165824);    // 442,368
  ushort_t* Wf2    = (ushort_t*)(ws + 25608192);    // 442,368
  float*    h2raw  = (float*)(ws + 26050560);       // 16,777,216
  float*    statsp = (float*)(ws + 42827776);       // 256 floats
  float *gsum1 = statsp, *gsq1 = statsp + 64, *gsum2 = statsp + 128, *gsq2 = statsp + 192;

  k_prep<<<5824, 256, 0, stream>>>(x, W1, W2, xb, Wf1, Wf2, statsp);

  k_conv<true><<<1024, 256, 0, stream>>>(xb, nbr, Wf1, (void*)h1pre, gsum1, gsq1);
  k_bn_relu<<<2048, 256, 0, stream>>>(h1pre, gsum1, gsq1, g1, b1, h1post);
  k_conv<false><<<1024, 256, 0, stream>>>(h1post, nbr, Wf2, (void*)h2raw, gsum2, gsq2);

  k_final<<<4096, 256, 0, stream>>>(h2raw, x, gsum2, gsq2, g2, b2, out);
}

// Round 9
// 223.267 us; speedup vs baseline: 1.2997x; 1.0579x over previous
//
#include <hip/hip_runtime.h>

typedef unsigned short ushort_t;
using bf16x8 = __attribute__((ext_vector_type(8))) short;
using f32x4  = __attribute__((ext_vector_type(4))) float;

#define KT 27
#define NV 65536

__device__ inline unsigned short f2bf(float f) {
  unsigned int u = __builtin_bit_cast(unsigned int, f);
  u += 0x7fffu + ((u >> 16) & 1u);
  return (unsigned short)(u >> 16);
}
__device__ inline float b2f(ushort_t u) {
  unsigned int x = ((unsigned int)u) << 16;
  return __builtin_bit_cast(float, x);
}

// merged prep: statsp zero (b0), x fp32->bf16 (b<4096),
// W1,W2 [k][c][d] -> per-lane 16x16x32 MFMA B frags (b 4096..5823):
// frag f = k*8 + nt*2 + kh;  Wf[f*512 + l*8 + j] = bf16(W[k][kh*32+(l>>4)*8+j][nt*16+(l&15)])
// so a B-frag load is wave-uniform base + lane*16B (coalesced, L2-hot).
__global__ __launch_bounds__(256) void k_prep(const float* __restrict__ x,
                                              const float* __restrict__ W1,
                                              const float* __restrict__ W2,
                                              ushort_t* __restrict__ xb,
                                              ushort_t* __restrict__ Wf1,
                                              ushort_t* __restrict__ Wf2,
                                              float* __restrict__ statsp) {
  int b = blockIdx.x;
  int t = threadIdx.x;
  if (b == 0) statsp[t] = 0.f;
  if (b < 4096) {
    int i = b * 256 + t;  // float4 index
    float4 v = ((const float4*)x)[i];
    ushort4 o;
    o.x = f2bf(v.x); o.y = f2bf(v.y); o.z = f2bf(v.z); o.w = f2bf(v.w);
    ((ushort4*)xb)[i] = o;
  } else {
    int e = (b - 4096) * 256 + t;  // < 442368
    const float* W = W1; ushort_t* Wf = Wf1;
    if (e >= 221184) { e -= 221184; W = W2; Wf = Wf2; }
    int j = e & 7, l = (e >> 3) & 63, f3 = (e >> 9) & 7, k = e >> 12;
    int nt = f3 >> 1, kh = f3 & 1;
    int c = kh * 32 + ((l >> 4) * 8) + j;
    int d = nt * 16 + (l & 15);
    Wf[e] = f2bf(W[(k << 12) + (c << 6) + d]);
  }
}

// Gather-GEMM conv, 16x16x32 MFMA, barrier-free K-loop, wave-local LDS.
// block = 256 thr = 4 independent waves; wave w owns 16 voxels, all 64 out ch.
// grid 1024 -> 4096 waves = 16 waves/CU (2x R5's TLP) - the safe TLP lever:
// tile shrink, not work split, so registers SHRINK (acc 16, rA 16, bB 32;
// ~100 total) and __launch_bounds__(256,4)'s 128 cap fits with no spill.
// A: depth-2 register pipeline -> wave-local LDS [row16][64ch], 16B-chunk slot
//    XOR-swizzled by row&7 (frag reads 2-way max = free). Same-wave DS ordering
//    means zero __syncthreads in the K-loop; plain register loads carry
//    compiler-guaranteed waits (the R8 glds race is structurally impossible).
// B: register-direct from pre-swizzled Wf, loaded per tap (L2-hot, TLP-covered).
template<bool OBF16>
__global__ __launch_bounds__(256, 4) void k_conv(const ushort_t* __restrict__ src,  // [N][64] bf16
                                                 const int* __restrict__ nbr,       // [N][27]
                                                 const ushort_t* __restrict__ Wf,
                                                 void* __restrict__ houtv,          // [N][64]
                                                 float* __restrict__ gsum,
                                                 float* __restrict__ gsq) {
  __shared__ alignas(16) ushort_t As[4][2][1024];  // per-wave double-buffered 16x64 tile, 16 KB
  __shared__ int nb_l[4][16 * KT];                 // per-wave rulebook rows, 6.9 KB
  __shared__ float red[2][4][64];                  // stats reduce, 2 KB

  const int t = threadIdx.x;
  const int lane = t & 63;
  const int w = t >> 6;
  const int m = lane & 15;         // voxel row within tile / output col within 16-tile
  const int quad = lane >> 4;
  const int wbase = blockIdx.x * 64 + w * 16;

  int* nbw = &nb_l[w][0];
  {
    const int* nbg = nbr + wbase * KT;
    for (int e = lane; e < 16 * KT; e += 64) nbw[e] = nbg[e];  // wave-local: no barrier
  }

  const int c0 = quad;             // this lane's source chunks (16B units): c0, c0+4
  const int r7 = m & 7;
  const int sl0 = (c0 ^ r7) * 8;   // swizzled LDS slots (ushort offsets)
  const int sl1 = ((c0 + 4) ^ r7) * 8;

  f32x4 acc[4] = {{0.f,0.f,0.f,0.f},{0.f,0.f,0.f,0.f},{0.f,0.f,0.f,0.f},{0.f,0.f,0.f,0.f}};

  uint4 rA[2][2];
  bf16x8 bB[8];

  auto ldA = [&](int k, uint4* r) {
    int idx = nbw[m * KT + k];
    uint4 v0 = {0u,0u,0u,0u}, v1 = {0u,0u,0u,0u};
    if (idx >= 0) {
      const ushort_t* p = src + idx * 64;
      v0 = *(const uint4*)(p + c0 * 8);
      v1 = *(const uint4*)(p + (c0 + 4) * 8);
    }
    r[0] = v0; r[1] = v1;
  };
  auto wrA = [&](int buf, const uint4* r) {
    ushort_t* a = &As[w][buf][m * 64];
    *(uint4*)(a + sl0) = r[0];
    *(uint4*)(a + sl1) = r[1];
  };
  auto ldB = [&](int k) {
    const ushort_t* p = Wf + k * 4096 + lane * 8;
#pragma unroll
    for (int u = 0; u < 8; ++u) bB[u] = *(const bf16x8*)(p + u * 512);
  };
  auto compute = [&](int buf) {
    const ushort_t* ar = &As[w][buf][m * 64];
    bf16x8 a0 = *(const bf16x8*)(ar + sl0);   // kk 0..31 (chunk quad)
    bf16x8 a1 = *(const bf16x8*)(ar + sl1);   // kk 32..63 (chunk quad+4)
#pragma unroll
    for (int nt = 0; nt < 4; ++nt) {
      acc[nt] = __builtin_amdgcn_mfma_f32_16x16x32_bf16(a0, bB[nt * 2 + 0], acc[nt], 0, 0, 0);
      acc[nt] = __builtin_amdgcn_mfma_f32_16x16x32_bf16(a1, bB[nt * 2 + 1], acc[nt], 0, 0, 0);
    }
  };

  // prologue: rA[0]=tap0, rA[1]=tap1, stage tap0 -> buf0
  ldA(0, rA[0]);
  ldA(1, rA[1]);
  wrA(0, rA[0]);

  // invariant at iter k: buf(k&1) staged with tap k; rA[(k+1)&1] holds tap k+1
#pragma unroll
  for (int k = 0; k < KT; ++k) {
    const int cur = k & 1, nxt = cur ^ 1;
    const int k2 = (k + 2 < KT) ? k + 2 : KT - 1;   // tail clamp (redundant, harmless)
    ldA(k2, rA[cur]);          // 2-iteration gather slack
    ldB(k);                    // L2-hot; sunk by compiler, covered by 16 waves/CU
    wrA(nxt, rA[nxt]);         // stage tap k+1
    compute(cur);              // tap k
  }

  // epilogue: store h + fused per-channel stats
  // C/D (16x16): col = lane&15, row = quad*4 + reg  [verified m89/m91]
  const int orow0 = wbase + quad * 4;
  float s[4], q[4];
#pragma unroll
  for (int nt = 0; nt < 4; ++nt) {
    float ss = 0.f, qq = 0.f;
#pragma unroll
    for (int r = 0; r < 4; ++r) {
      float v = acc[nt][r];
      int row = orow0 + r;
      if (OBF16) ((ushort_t*)houtv)[row * 64 + nt * 16 + m] = f2bf(v);
      else       ((float*)houtv)[row * 64 + nt * 16 + m] = v;
      ss += v; qq += v * v;
    }
    s[nt] = ss; q[nt] = qq;
  }
#pragma unroll
  for (int nt = 0; nt < 4; ++nt) {
    s[nt] += __shfl_xor(s[nt], 16, 64); s[nt] += __shfl_xor(s[nt], 32, 64);
    q[nt] += __shfl_xor(q[nt], 16, 64); q[nt] += __shfl_xor(q[nt], 32, 64);
  }
  if (quad == 0) {
#pragma unroll
    for (int nt = 0; nt < 4; ++nt) {
      red[0][w][nt * 16 + m] = s[nt];
      red[1][w][nt * 16 + m] = q[nt];
    }
  }
  __syncthreads();   // only barrier in the kernel
  if (t < 128) {
    int which = t >> 6, c = t & 63;
    float v = red[which][0][c] + red[which][1][c] + red[which][2][c] + red[which][3][c];
    atomicAdd((which ? gsq : gsum) + c, v);
  }
}

// BN1 (inline params from raw stats) + ReLU on bf16 h1, writes bf16 for conv2's gather
__global__ __launch_bounds__(256) void k_bn_relu(const ushort_t* __restrict__ h,
                                                 const float* __restrict__ gsum,
                                                 const float* __restrict__ gsq,
                                                 const float* __restrict__ gamma,
                                                 const float* __restrict__ beta,
                                                 ushort_t* __restrict__ ob) {
  __shared__ float sc[64], sh[64];
  int t = threadIdx.x;
  if (t < 64) {
    float mean = gsum[t] * (1.f / NV);
    float var = gsq[t] * (1.f / NV) - mean * mean;
    float rs = rsqrtf(var + 1e-5f);
    float s = gamma[t] * rs;
    sc[t] = s;
    sh[t] = beta[t] - mean * s;
  }
  __syncthreads();
  int i = blockIdx.x * 256 + t;    // uint4 index = 8 bf16
  int c0 = (i & 7) * 8;
  uint4 v = ((const uint4*)h)[i];
  const ushort_t* pu = (const ushort_t*)&v;
  uint4 o;
  ushort_t* po = (ushort_t*)&o;
#pragma unroll
  for (int n = 0; n < 8; ++n)
    po[n] = f2bf(fmaxf(0.f, b2f(pu[n]) * sc[c0 + n] + sh[c0 + n]));
  ((uint4*)ob)[i] = o;
}

// BN2 (inline params) + residual + ReLU, fp32 out
__global__ __launch_bounds__(256) void k_final(const float* __restrict__ h,
                                               const float* __restrict__ x,
                                               const float* __restrict__ gsum,
                                               const float* __restrict__ gsq,
                                               const float* __restrict__ gamma,
                                               const float* __restrict__ beta,
                                               float* __restrict__ out) {
  __shared__ float sc[64], sh[64];
  int t = threadIdx.x;
  if (t < 64) {
    float mean = gsum[t] * (1.f / NV);
    float var = gsq[t] * (1.f / NV) - mean * mean;
    float rs = rsqrtf(var + 1e-5f);
    float s = gamma[t] * rs;
    sc[t] = s;
    sh[t] = beta[t] - mean * s;
  }
  __syncthreads();
  int i = blockIdx.x * 256 + t;
  int c0 = (i << 2) & 63;
  float4 v = ((const float4*)h)[i];
  float4 xv = ((const float4*)x)[i];
  float4 o;
  o.x = fmaxf(0.f, v.x * sc[c0]     + sh[c0]     + xv.x);
  o.y = fmaxf(0.f, v.y * sc[c0 + 1] + sh[c0 + 1] + xv.y);
  o.z = fmaxf(0.f, v.z * sc[c0 + 2] + sh[c0 + 2] + xv.z);
  o.w = fmaxf(0.f, v.w * sc[c0 + 3] + sh[c0 + 3] + xv.w);
  ((float4*)out)[i] = o;
}

extern "C" void kernel_launch(void* const* d_in, const int* in_sizes, int n_in,
                              void* d_out, int out_size, void* d_ws, size_t ws_size,
                              hipStream_t stream) {
  const float* x   = (const float*)d_in[0];
  const int*   nbr = (const int*)d_in[1];
  const float* W1  = (const float*)d_in[2];
  const float* g1  = (const float*)d_in[3];
  const float* b1  = (const float*)d_in[4];
  const float* W2  = (const float*)d_in[5];
  const float* g2  = (const float*)d_in[6];
  const float* b2  = (const float*)d_in[7];
  float* out = (float*)d_out;
  char* ws = (char*)d_ws;

  // workspace layout (bytes, 256-aligned), total ~42.8 MB
  ushort_t* xb     = (ushort_t*)(ws);               // 8,388,608
  ushort_t* h1pre  = (ushort_t*)(ws + 8388608);     // 8,388,608 (bf16, pre-BN)
  ushort_t* h1post = (ushort_t*)(ws + 16777216);    // 8,388,608 (bf16, post-BN+ReLU)
  ushort_t* Wf1    = (ushort_t*)(ws + 25165824);    // 442,368
  ushort_t* Wf2    = (ushort_t*)(ws + 25608192);    // 442,368
  float*    h2raw  = (float*)(ws + 26050560);       // 16,777,216
  float*    statsp = (float*)(ws + 42827776);       // 256 floats
  float *gsum1 = statsp, *gsq1 = statsp + 64, *gsum2 = statsp + 128, *gsq2 = statsp + 192;

  k_prep<<<5824, 256, 0, stream>>>(x, W1, W2, xb, Wf1, Wf2, statsp);

  k_conv<true><<<1024, 256, 0, stream>>>(xb, nbr, Wf1, (void*)h1pre, gsum1, gsq1);
  k_bn_relu<<<2048, 256, 0, stream>>>(h1pre, gsum1, gsq1, g1, b1, h1post);
  k_conv<false><<<1024, 256, 0, stream>>>(h1post, nbr, Wf2, (void*)h2raw, gsum2, gsq2);

  k_final<<<4096, 256, 0, stream>>>(h2raw, x, gsum2, gsq2, g2, b2, out);
}